// Round 16
// baseline (229.558 us; speedup 1.0000x reference)
//
#include <hip/hip_runtime.h>
#include <hip/hip_bf16.h>

#define E 256
#define H 8
#define HD 32
#define T 768
#define B 4
#define BH 32
// segments: L=[0,300), A=[300,550), V=[550,768)

typedef __attribute__((ext_vector_type(8))) short bf16x8;
typedef __attribute__((ext_vector_type(4))) float f32x4;

__device__ __forceinline__ float b2f(__hip_bfloat16 x) { return __bfloat162float(x); }

__device__ __forceinline__ unsigned short f2bf_u(float x) {
    __hip_bfloat16 h = __float2bfloat16(x);
    return *(unsigned short*)&h;
}
__device__ __forceinline__ float bfu2f(unsigned short u) {
    return __uint_as_float(((unsigned int)u) << 16);
}

// split fp32[8] -> bf16 hi + lo fragments
__device__ __forceinline__ void f8_split(const float* v, bf16x8& h, bf16x8& l) {
    #pragma unroll
    for (int e = 0; e < 8; ++e) {
        unsigned short hu = f2bf_u(v[e]);
        h[e] = (short)hu;
        l[e] = (short)f2bf_u(v[e] - bfu2f(hu));
    }
}

#define MFMA3(ACC, AH, AL, BH_, BL_)                                         \
    ACC = __builtin_amdgcn_mfma_f32_16x16x32_bf16(AH, BH_, ACC, 0, 0, 0);    \
    ACC = __builtin_amdgcn_mfma_f32_16x16x32_bf16(AH, BL_, ACC, 0, 0, 0);    \
    ACC = __builtin_amdgcn_mfma_f32_16x16x32_bf16(AL, BH_, ACC, 0, 0, 0);

// dtype-agnostic scalar load: f32 ? float : bf16
__device__ __forceinline__ float ldu(const void* p, size_t i, int f32) {
    if (f32) return ((const float*)p)[i];
    return b2f(((const __hip_bfloat16*)p)[i]);
}

// ---------------------------------------------------------------------------
// Kernel 0: input dtype detection (fp32 read as bf16 -> garbage exponents).
// ---------------------------------------------------------------------------
__global__ void detect_kernel(const unsigned short* __restrict__ q,
                              int* __restrict__ flag) {
    if (threadIdx.x == 0 && blockIdx.x == 0) {
        int f32 = 0;
        for (int i = 0; i < 256; ++i) {
            unsigned int bits = ((unsigned int)q[i]) << 16;
            float v = __uint_as_float(bits);
            if (!(v == v) || fabsf(v) > 1e4f) f32 = 1;
        }
        *flag = f32;
    }
}

// ---------------------------------------------------------------------------
// Kernel 1: QKV projection (r12 core). Round-16 epilogue: q -> fp32 qws
// (unchanged); k/v -> bf16 hi/lo FRAGMENTS in global (the exact layout the
// attn MFMAs consume), computed ONCE here instead of per-t-tile in attn.
//   k: B[n=s16][k=hd]  lane=(s&15)|((hd>>3)<<4), j=hd&7, slot [bh][ch][sb]
//   v: B[n=hd16][k=s32] lane=(hd&15)|(((s>>3)&3)<<4), j=s&7, slot [bh][ch][hdb][ks]
// ---------------------------------------------------------------------------
__global__ __launch_bounds__(256) void qkv_gemm_kernel(
    const void* query, const void* key, const void* value,
    const void* w, const void* bias, const int* __restrict__ flag,
    float* __restrict__ qws,
    unsigned short* __restrict__ KGh, unsigned short* __restrict__ KGl,
    unsigned short* __restrict__ VGh, unsigned short* __restrict__ VGl)
{
    int f32 = *flag;
    int bx = blockIdx.x;              // 0..11 col tiles
    int by = blockIdx.y;              // 0..47 row tiles
    int sec = bx >> 2;                // 0=q, 1=k, 2=v
    const void* X = (sec == 0) ? query : (sec == 1) ? key : value;
    int colbase = bx * 64;
    int rowbase = by * 64;
    int tid = threadIdx.x;
    int tx = tid & 15, ty = tid >> 4;
    __shared__ __align__(16) float AsT[32][68];   // [kk][row]
    __shared__ __align__(16) float Bs[32][68];    // [kk][col]
    float acc[4][4] = {};

    for (int kb = 0; kb < 8; ++kb) {
        __syncthreads();
        if (f32) {
            const float4* Xg = (const float4*)((const float*)X +
                                (size_t)rowbase * 256 + kb * 32);
            const float4* Wg = (const float4*)((const float*)w +
                                (size_t)colbase * 256 + kb * 32);
            #pragma unroll
            for (int l = 0; l < 2; ++l) {
                int idx4 = l * 256 + tid;
                int r = idx4 >> 3, kq = idx4 & 7;
                float4 xv = Xg[(size_t)r * 64 + kq];
                AsT[kq * 4 + 0][r] = xv.x;
                AsT[kq * 4 + 1][r] = xv.y;
                AsT[kq * 4 + 2][r] = xv.z;
                AsT[kq * 4 + 3][r] = xv.w;
                float4 wv = Wg[(size_t)r * 64 + kq];
                Bs[kq * 4 + 0][r] = wv.x;
                Bs[kq * 4 + 1][r] = wv.y;
                Bs[kq * 4 + 2][r] = wv.z;
                Bs[kq * 4 + 3][r] = wv.w;
            }
        } else {
            #pragma unroll
            for (int l = 0; l < 2; ++l) {
                int idx4 = l * 256 + tid;
                int r = idx4 >> 3, kq = idx4 & 7;
                #pragma unroll
                for (int j = 0; j < 4; ++j) {
                    AsT[kq * 4 + j][r] =
                        ldu(X, (size_t)(rowbase + r) * 256 + kb * 32 + kq * 4 + j, 0);
                    Bs[kq * 4 + j][r] =
                        ldu(w, (size_t)(colbase + r) * 256 + kb * 32 + kq * 4 + j, 0);
                }
            }
        }
        __syncthreads();
        #pragma unroll 8
        for (int kk = 0; kk < 32; ++kk) {
            const float4 av = *(const float4*)&AsT[kk][ty * 4];
            const float4 bv = *(const float4*)&Bs[kk][tx * 4];
            acc[0][0] += av.x * bv.x; acc[0][1] += av.x * bv.y;
            acc[0][2] += av.x * bv.z; acc[0][3] += av.x * bv.w;
            acc[1][0] += av.y * bv.x; acc[1][1] += av.y * bv.y;
            acc[1][2] += av.y * bv.z; acc[1][3] += av.y * bv.w;
            acc[2][0] += av.z * bv.x; acc[2][1] += av.z * bv.y;
            acc[2][2] += av.z * bv.z; acc[2][3] += av.z * bv.w;
            acc[3][0] += av.w * bv.x; acc[3][1] += av.w * bv.y;
            acc[3][2] += av.w * bv.z; acc[3][3] += av.w * bv.w;
        }
    }

    if (sec == 0) {
        #pragma unroll
        for (int u = 0; u < 4; ++u)
            #pragma unroll
            for (int v = 0; v < 4; ++v) {
                int r = rowbase + ty * 4 + u;
                int cg = colbase + tx * 4 + v;
                float val = (acc[u][v] + ldu(bias, cg, f32)) * 0.17677669529663687f;
                int e_local = cg & 255;
                int h = e_local >> 5, hd = e_local & 31;
                int t = r >> 2, b = r & 3;
                qws[((size_t)((b * H + h) * T + t)) * HD + hd] = val;
            }
    } else {
        unsigned short* Gh = (sec == 1) ? KGh : VGh;
        unsigned short* Gl = (sec == 1) ? KGl : VGl;
        #pragma unroll
        for (int u = 0; u < 4; ++u) {
            int r = rowbase + ty * 4 + u;
            int t = r >> 2, b = r & 3;            // t = s index; b = batch
            int cg0 = colbase + tx * 4;
            int e0 = cg0 & 255;
            int h = e0 >> 5, hd0 = e0 & 31;
            int bh = b * 8 + h;
            int ch = t >> 6;
            unsigned short hi[4], lo[4];
            #pragma unroll
            for (int v = 0; v < 4; ++v) {
                float val = acc[u][v] + ldu(bias, cg0 + v, f32);
                hi[v] = f2bf_u(val);
                lo[v] = f2bf_u(val - bfu2f(hi[v]));
            }
            if (sec == 1) {
                int lane_k = (t & 15) | ((hd0 >> 3) << 4);
                size_t bi = (((size_t)(bh * 12 + ch) * 4 + ((t >> 4) & 3)) * 64
                             + lane_k) * 8 + (hd0 & 7);
                ushort4 h4 = {hi[0], hi[1], hi[2], hi[3]};
                ushort4 l4 = {lo[0], lo[1], lo[2], lo[3]};
                *(ushort4*)&Gh[bi] = h4;
                *(ushort4*)&Gl[bi] = l4;
            } else {
                int sl = t & 63, ks = sl >> 5, j = sl & 7, q3 = (sl >> 3) & 3;
                #pragma unroll
                for (int v = 0; v < 4; ++v) {
                    int hd = hd0 + v, hdb = hd >> 4;
                    size_t bi = ((((size_t)(bh * 12 + ch) * 2 + hdb) * 2 + ks) * 64
                                 + ((hd & 15) | (q3 << 4))) * 8 + j;
                    Gh[bi] = hi[v];
                    Gl[bi] = lo[v];
                }
            }
        }
    }
}

// ---------------------------------------------------------------------------
// Kernel 2 (round-16): MFMA attention, no k/v staging — fragments loaded
// directly from qkv's global hi/lo buffers (L2-hot, reused by 24 t-tiles).
// EPK double-buffered -> ONE sync per chunk. PL aliases dead EPK.
// ---------------------------------------------------------------------------
__global__ __launch_bounds__(256) void attn_mfma_kernel(
    const float* __restrict__ qws,
    const unsigned short* __restrict__ KGh, const unsigned short* __restrict__ KGl,
    const unsigned short* __restrict__ VGh, const unsigned short* __restrict__ VGl,
    unsigned short* __restrict__ Ohi, unsigned short* __restrict__ Olo)
{
    int tile = blockIdx.x;       // 0..23
    int bh   = blockIdx.y;       // 0..31
    int t0 = tile * 32;
    int tid = threadIdx.x;
    int w = tid >> 6, lane = tid & 63;
    int m = lane & 15, quad = lane >> 4;
    int tb = w & 1, hdb = w >> 1;

    __shared__ __align__(16) unsigned int EPK[2][2048];  // [buf][(tb*2+ks)*512+lane*8+j]
    __shared__ float SP[4][16][3];
    float* PL = (float*)&EPK[0][0];                      // alias: EPK dead at epilogue

    // q fragment (chunk-invariant, registers): A[m=t16][k=hd]
    bf16x8 aqh, aql;
    {
        const float* qr = qws + ((size_t)bh * T + t0 + tb * 16 + m) * HD + quad * 8;
        float qv[8];
        *(float4*)&qv[0] = *(const float4*)qr;
        *(float4*)&qv[4] = *(const float4*)(qr + 4);
        f8_split(qv, aqh, aql);
    }

    f32x4 acc0 = {}, acc1 = {}, acc2 = {};
    float ss0[4] = {}, ss1[4] = {}, ss2[4] = {};

    for (int ch = 0; ch < 12; ++ch) {
        int base = ch * 64;
        int buf = ch & 1;
        // --- scores + exp + e_frag writes (k fragments straight from global) ---
        #pragma unroll
        for (int sbi = 0; sbi < 2; ++sbi) {
            int sb = (w >> 1) * 2 + sbi;
            size_t kfi = (((size_t)(bh * 12 + ch) * 4 + sb) * 64 + lane) * 8;
            bf16x8 bkh = *(const bf16x8*)(KGh + kfi);
            bf16x8 bkl = *(const bf16x8*)(KGl + kfi);
            f32x4 d = {};
            MFMA3(d, aqh, aql, bkh, bkl)
            int s64 = sb * 16 + m;           // s within chunk (C/D col)
            int sglob = base + s64;
            int ksw = s64 >> 5, qp = (s64 >> 3) & 3, jp = m & 7;
            unsigned int* eb = &EPK[buf][(tb * 2 + ksw) * 512 + jp];
            #pragma unroll
            for (int r = 0; r < 4; ++r) {
                float e = __expf(d[r]);
                if (sglob < 300) ss0[r] += e;
                else if (sglob < 550) ss1[r] += e;
                else ss2[r] += e;
                unsigned short hu = f2bf_u(e);
                unsigned short lu = f2bf_u(e - bfu2f(hu));
                eb[((quad * 4 + r) + 16 * qp) * 8] =
                    (unsigned int)hu | ((unsigned int)lu << 16);
            }
        }
        __syncthreads();

        // --- PV: wave's (tb, hdb) tile, 2 k-steps; v fragments from global ---
        #pragma unroll
        for (int ks = 0; ks < 2; ++ks) {
            const unsigned int* ep = &EPK[buf][((tb * 2 + ks) * 64 + lane) * 8];
            uint4 p0 = *(const uint4*)ep;
            uint4 p1 = *(const uint4*)(ep + 4);
            bf16x8 aeh, ael;
            aeh[0] = (short)(p0.x & 0xffff); ael[0] = (short)(p0.x >> 16);
            aeh[1] = (short)(p0.y & 0xffff); ael[1] = (short)(p0.y >> 16);
            aeh[2] = (short)(p0.z & 0xffff); ael[2] = (short)(p0.z >> 16);
            aeh[3] = (short)(p0.w & 0xffff); ael[3] = (short)(p0.w >> 16);
            aeh[4] = (short)(p1.x & 0xffff); ael[4] = (short)(p1.x >> 16);
            aeh[5] = (short)(p1.y & 0xffff); ael[5] = (short)(p1.y >> 16);
            aeh[6] = (short)(p1.z & 0xffff); ael[6] = (short)(p1.z >> 16);
            aeh[7] = (short)(p1.w & 0xffff); ael[7] = (short)(p1.w >> 16);
            size_t vfi = ((((size_t)(bh * 12 + ch) * 2 + hdb) * 2 + ks) * 64 + lane) * 8;
            bf16x8 bvh = *(const bf16x8*)(VGh + vfi);
            bf16x8 bvl = *(const bf16x8*)(VGl + vfi);
            int s_lo = base + ks * 32;
            if (s_lo + 32 <= 300) { MFMA3(acc0, aeh, ael, bvh, bvl) }
            else if (s_lo >= 300 && s_lo + 32 <= 550) { MFMA3(acc1, aeh, ael, bvh, bvl) }
            else if (s_lo >= 550) { MFMA3(acc2, aeh, ael, bvh, bvl) }
            else {
                int bnd = (s_lo < 300) ? 300 : 550;
                bf16x8 eha = aeh, ela = ael, ehb = aeh, elb = ael;
                #pragma unroll
                for (int j = 0; j < 8; ++j) {
                    int s = s_lo + quad * 8 + j;
                    if (s < bnd) { ehb[j] = 0; elb[j] = 0; }
                    else         { eha[j] = 0; ela[j] = 0; }
                }
                if (s_lo < 300) { MFMA3(acc0, eha, ela, bvh, bvl)
                                  MFMA3(acc1, ehb, elb, bvh, bvl) }
                else            { MFMA3(acc1, eha, ela, bvh, bvl)
                                  MFMA3(acc2, ehb, elb, bvh, bvl) }
            }
        }
    }

    // S partials: reduce over the 16 s-lanes, SP[w][t16][seg].
    #pragma unroll
    for (int sg = 0; sg < 3; ++sg)
        #pragma unroll
        for (int r = 0; r < 4; ++r) {
            float v = (sg == 0) ? ss0[r] : (sg == 1) ? ss1[r] : ss2[r];
            v += __shfl_down(v, 8, 16);
            v += __shfl_down(v, 4, 16);
            v += __shfl_down(v, 2, 16);
            v += __shfl_down(v, 1, 16);
            if (m == 0) SP[w][quad * 4 + r][sg] = v;
        }
    __syncthreads();   // all PV reads of EPK done -> safe to alias PL over it

    // P (C/D layout) -> PL[seg][t32][hd32] (stride 36)
    #pragma unroll
    for (int r = 0; r < 4; ++r) {
        int t32 = tb * 16 + quad * 4 + r;
        int hd = hdb * 16 + m;
        PL[0 * 1152 + t32 * 36 + hd] = acc0[r];
        PL[1 * 1152 + t32 * 36 + hd] = acc1[r];
        PL[2 * 1152 + t32 * 36 + hd] = acc2[r];
    }
    __syncthreads();

    // Epilogue (r13-proven): tt=t-row, q4=hd-quad; fragment-major O store.
    int tt = tid >> 3, q4 = tid & 7;
    float Pv[3][4];
    #pragma unroll
    for (int sg = 0; sg < 3; ++sg) {
        const float4 p = *(const float4*)&PL[sg * 1152 + tt * 36 + q4 * 4];
        Pv[sg][0] = p.x; Pv[sg][1] = p.y; Pv[sg][2] = p.z; Pv[sg][3] = p.w;
    }
    int tbe = tt >> 4, t16 = tt & 15;
    float S0 = SP[tbe][t16][0] + SP[tbe + 2][t16][0];
    float S1 = SP[tbe][t16][1] + SP[tbe + 2][t16][1];
    float S2 = SP[tbe][t16][2] + SP[tbe + 2][t16][2];

    int t_glob = t0 + tt;
    int g = (t_glob < 300) ? 0 : (t_glob < 550 ? 1 : 2);
    int b_ = bh >> 3, h_ = bh & 7;
    int row = t_glob * B + b_;
    int lslot = (row & 15) + ((q4 >> 1) << 4);
    int j0 = (q4 & 1) * 4;
    size_t fbase = (((size_t)(row >> 4) * 56 + h_) * 64 + lslot) * 8 + j0;
    const int masks[7] = {7, 3, 5, 6, 1, 2, 4};  // LAV,LA,LV,AV,L,A,V
    #pragma unroll
    for (int i = 0; i < 7; ++i) {
        int mm = masks[i];
        float n0 = 0.f, n1 = 0.f, n2 = 0.f, n3 = 0.f, den = 0.f;
        if (mm & 1) { n0 += Pv[0][0]; n1 += Pv[0][1]; n2 += Pv[0][2]; n3 += Pv[0][3]; den += S0; }
        if (mm & 2) { n0 += Pv[1][0]; n1 += Pv[1][1]; n2 += Pv[1][2]; n3 += Pv[1][3]; den += S1; }
        if (mm & 4) { n0 += Pv[2][0]; n1 += Pv[2][1]; n2 += Pv[2][2]; n3 += Pv[2][3]; den += S2; }
        float r = 1.f / den;
        int live = (mm >> g) & 1;
        float o[4];
        o[0] = live ? n0 * r : 0.f;
        o[1] = live ? n1 * r : 0.f;
        o[2] = live ? n2 * r : 0.f;
        o[3] = live ? n3 * r : 0.f;
        ushort4 hi4, lo4;
        unsigned short* hp = (unsigned short*)&hi4;
        unsigned short* lp = (unsigned short*)&lo4;
        #pragma unroll
        for (int j = 0; j < 4; ++j) {
            unsigned short hu = f2bf_u(o[j]);
            hp[j] = hu;
            lp[j] = f2bf_u(o[j] - bfu2f(hu));
        }
        size_t addr = fbase + (size_t)i * (8 * 64 * 8);
        *(ushort4*)&Ohi[addr] = hi4;
        *(ushort4*)&Olo[addr] = lo4;
    }
}

// ---------------------------------------------------------------------------
// Weight combination: D_i = (final_w @ G_i @ out_w[i])^T stacked as (1792,256).
// ---------------------------------------------------------------------------
__device__ __forceinline__ float gsum_load(int i, int r2, int r,
                                           const void* sl, const void* sa,
                                           const void* sv, int f32)
{
    size_t base = (size_t)r2 * 1024;
    switch (i) {
        case 0: return ldu(sl, base + r, f32) + ldu(sa, base + r, f32) + ldu(sv, base + r, f32);
        case 1: return ldu(sl, base + 256 + r, f32) + ldu(sa, base + 256 + r, f32);
        case 2: return ldu(sl, base + 512 + r, f32) + ldu(sv, base + 256 + r, f32);
        case 3: return ldu(sa, base + 512 + r, f32) + ldu(sv, base + 512 + r, f32);
        case 4: return ldu(sl, base + 768 + r, f32);
        case 5: return ldu(sa, base + 768 + r, f32);
        default: return ldu(sv, base + 768 + r, f32);
    }
}

// Mtmp_i = G_i @ out_w[i]    (proven round-2)
__global__ __launch_bounds__(256) void wcomb1_kernel(
    const void* sl, const void* sa, const void* sv, const void* outw,
    const int* __restrict__ flag, float* __restrict__ Mtmp)
{
    int f32 = *flag;
    int bid = blockIdx.x;
    int i = bid >> 8, r2 = bid & 255;
    int c = threadIdx.x;
    __shared__ float g[256];
    g[c] = gsum_load(i, r2, c, sl, sa, sv, f32);
    __syncthreads();
    float acc = 0.f;
    for (int r = 0; r < 256; ++r)
        acc += g[r] * ldu(outw, (size_t)i * 65536 + r * 256 + c, f32);
    Mtmp[(size_t)i * 65536 + r2 * 256 + c] = acc;
}

// DT hi/lo fragment-major (proven round-15: 32x32 tiles, grid (8,8,7)).
__global__ __launch_bounds__(256) void wcomb2_gemm_kernel(
    const float* __restrict__ Mtmp, const void* finalw,
    const int* __restrict__ flag,
    unsigned short* __restrict__ DThi, unsigned short* __restrict__ DTlo)
{
    int f32 = *flag;
    int bx = blockIdx.x;   // e tile 0..7 (32 cols)
    int by = blockIdx.y;   // c tile 0..7 (32 rows)
    int i  = blockIdx.z;   // branch 0..6
    int tid = threadIdx.x;
    int tx = tid & 15, ty = tid >> 4;
    int colbase = bx * 32, rowbase = by * 32;
    __shared__ __align__(16) float AsT[32][34];   // [kk][c]
    __shared__ __align__(16) float Bs[32][34];    // [kk][e]
    float acc[2][2] = {};

    for (int kb = 0; kb < 8; ++kb) {
        __syncthreads();
        #pragma unroll
        for (int l = 0; l < 4; ++l) {
            int idx = l * 256 + tid;
            int c = idx & 31, kk = idx >> 5;
            AsT[kk][c] = Mtmp[(size_t)i * 65536 + (kb * 32 + kk) * 256 + rowbase + c];
            int k2 = idx & 31, n = idx >> 5;
            Bs[k2][n] = ldu(finalw, (size_t)(colbase + n) * 256 + kb * 32 + k2, f32);
        }
        __syncthreads();
        #pragma unroll 8
        for (int kk = 0; kk < 32; ++kk) {
            const float2 av = *(const float2*)&AsT[kk][ty * 2];
            const float2 bv = *(const float2*)&Bs[kk][tx * 2];
            acc[0][0] += av.x * bv.x; acc[0][1] += av.x * bv.y;
            acc[1][0] += av.y * bv.x; acc[1][1] += av.y * bv.y;
        }
    }
    #pragma unroll
    for (int u = 0; u < 2; ++u)
        #pragma unroll
        for (int v = 0; v < 2; ++v) {
            int c = rowbase + ty * 2 + u, e = colbase + tx * 2 + v;
            float a = acc[u][v];
            unsigned short hu = f2bf_u(a);
            size_t fidx = (((size_t)(e >> 4) * 56 + i * 8 + (c >> 5)) * 64
                           + (e & 15) + (((c >> 3) & 3) << 4)) * 8 + (c & 7);
            DThi[fidx] = hu;
            DTlo[fidx] = f2bf_u(a - bfu2f(hu));
        }
}

// ---------------------------------------------------------------------------
// Bias path (proven round-5). c0 ALIASES Mtmp (dead after wcomb2).
// ---------------------------------------------------------------------------
__global__ __launch_bounds__(256) void bias1_kernel(
    const void* sl, const void* sa, const void* sv, const void* outb,
    const void* slb, const void* sab, const void* svb,
    const int* __restrict__ flag, float* __restrict__ c0)
{
    int f32 = *flag;
    int r2 = blockIdx.x, m = threadIdx.x;
    __shared__ float red[256];
    float acc = 0.f;
    #pragma unroll
    for (int i = 0; i < 7; ++i)
        acc += ldu(outb, i * 256 + m, f32) * gsum_load(i, r2, m, sl, sa, sv, f32);
    red[m] = acc;
    __syncthreads();
    for (int s = 128; s > 0; s >>= 1) {
        if (m < s) red[m] += red[m + s];
        __syncthreads();
    }
    if (m == 0)
        c0[r2] = red[0] + ldu(slb, r2, f32) + ldu(sab, r2, f32) + ldu(svb, r2, f32);
}

__global__ __launch_bounds__(256) void bias2_kernel(
    const float* __restrict__ c0, const void* finalw, const void* finalb,
    const int* __restrict__ flag, float* __restrict__ d0)
{
    int f32 = *flag;
    int e = blockIdx.x, r = threadIdx.x;
    __shared__ float red[256];
    red[r] = c0[r] * ldu(finalw, (size_t)e * 256 + r, f32);
    __syncthreads();
    for (int s = 128; s > 0; s >>= 1) {
        if (r < s) red[r] += red[r + s];
        __syncthreads();
    }
    if (r == 0)
        d0[e] = red[0] + ldu(finalb, e, f32);
}

// ---------------------------------------------------------------------------
// Kernel 4 (proven round-13, MFMA + fragment-major): result = O@Dstack + d0.
// ---------------------------------------------------------------------------
__global__ __launch_bounds__(256) void final_gemm_mfma_kernel(
    const unsigned short* __restrict__ Ohi, const unsigned short* __restrict__ Olo,
    const unsigned short* __restrict__ DThi, const unsigned short* __restrict__ DTlo,
    const float* __restrict__ d0, const int* __restrict__ flag,
    void* __restrict__ outv)
{
    int f32 = *flag;
    int bx = blockIdx.x;          // col group 0..3 (64 cols)
    int by = blockIdx.y;          // row group 0..191 (16 rows)
    int w  = threadIdx.x >> 6;    // wave 0..3
    int lane = threadIdx.x & 63;
    int m = lane & 15, quad = lane >> 4;
    int R0 = by * 16, C0 = bx * 64 + w * 16;

    int t0 = R0 >> 2, t1 = (R0 + 15) >> 2;
    int g0 = (t0 < 300) ? 0 : (t0 < 550 ? 1 : 2);
    int g1 = (t1 < 300) ? 0 : (t1 < 550 ? 1 : 2);
    int activeset = (1 << g0) | (1 << g1);
    const int masks[7] = {7, 3, 5, 6, 1, 2, 4};

    const unsigned short* Abase_h = Ohi + (size_t)by * 56 * 512 + lane * 8;
    const unsigned short* Abase_l = Olo + (size_t)by * 56 * 512 + lane * 8;
    const unsigned short* Bbase_h = DThi + (size_t)(bx * 4 + w) * 56 * 512 + lane * 8;
    const unsigned short* Bbase_l = DTlo + (size_t)(bx * 4 + w) * 56 * 512 + lane * 8;

    f32x4 acc = {};
    for (int i = 0; i < 7; ++i) {
        if (!(masks[i] & activeset)) continue;
        #pragma unroll
        for (int kb = 0; kb < 8; ++kb) {
            size_t off = (size_t)(i * 8 + kb) * 512;
            bf16x8 ah = *(const bf16x8*)(Abase_h + off);
            bf16x8 al = *(const bf16x8*)(Abase_l + off);
            bf16x8 bh = *(const bf16x8*)(Bbase_h + off);
            bf16x8 bl = *(const bf16x8*)(Bbase_l + off);
            acc = __builtin_amdgcn_mfma_f32_16x16x32_bf16(ah, bh, acc, 0, 0, 0);
            acc = __builtin_amdgcn_mfma_f32_16x16x32_bf16(ah, bl, acc, 0, 0, 0);
            acc = __builtin_amdgcn_mfma_f32_16x16x32_bf16(al, bh, acc, 0, 0, 0);
        }
    }
    float dv = d0[C0 + m];
    #pragma unroll
    for (int r = 0; r < 4; ++r) {
        int row = R0 + quad * 4 + r;
        int col = C0 + m;
        float val = acc[r] + dv;
        if (f32) ((float*)outv)[(size_t)row * 256 + col] = val;
        else ((__hip_bfloat16*)outv)[(size_t)row * 256 + col] = __float2bfloat16(val);
    }
}

// ---------------------------------------------------------------------------
extern "C" void kernel_launch(void* const* d_in, const int* in_sizes, int n_in,
                              void* d_out, int out_size, void* d_ws, size_t ws_size,
                              hipStream_t stream) {
    const void* query     = d_in[0];
    const void* key       = d_in[1];
    const void* value     = d_in[2];
    const void* in_proj_w = d_in[3];
    const void* in_proj_b = d_in[4];
    const void* out_w     = d_in[5];
    const void* out_b     = d_in[6];
    const void* s_l_w     = d_in[7];
    const void* s_l_b     = d_in[8];
    const void* s_a_w     = d_in[9];
    const void* s_a_b     = d_in[10];
    const void* s_v_w     = d_in[11];
    const void* s_v_b     = d_in[12];
    const void* final_w   = d_in[13];
    const void* final_b   = d_in[14];

    float* ws     = (float*)d_ws;
    float* qws    = ws;                 //   786432 f (q fp32)
    // kws region (786432 f) = k hi/lo bf16 fragments (786432 each):
    unsigned short* KGh = (unsigned short*)(ws + 786432);
    unsigned short* KGl = KGh + 786432;
    // vws region (786432 f) = v hi/lo bf16 fragments:
    unsigned short* VGh = (unsigned short*)(ws + 1572864);
    unsigned short* VGl = VGh + 786432;
    unsigned short* Ohi = (unsigned short*)(ws + 2359296);   // 5505024 bf16
    unsigned short* Olo = (unsigned short*)(ws + 5111808);   // 5505024 bf16
    float* Mtmp   = ws + 7864320;       //   458752 f
    unsigned short* DThi = (unsigned short*)(ws + 8323072);  // 458752 bf16
    unsigned short* DTlo = (unsigned short*)(ws + 8552448);  // 458752 bf16
    float* d0     = ws + 8781824;       //      256 f
    int*   flag   = (int*)(ws + 8782080);  // 1 int — proven footprint HIGH-WATER
    float* c0     = Mtmp;               // ALIAS: Mtmp dead after wcomb2

    detect_kernel<<<1, 64, 0, stream>>>((const unsigned short*)query, flag);
    qkv_gemm_kernel<<<dim3(12, 48), 256, 0, stream>>>(query, key, value,
                                                      in_proj_w, in_proj_b, flag,
                                                      qws, KGh, KGl, VGh, VGl);
    wcomb1_kernel<<<7 * 256, 256, 0, stream>>>(s_l_w, s_a_w, s_v_w, out_w, flag, Mtmp);
    attn_mfma_kernel<<<dim3(24, 32), 256, 0, stream>>>(qws, KGh, KGl, VGh, VGl,
                                                       Ohi, Olo);
    wcomb2_gemm_kernel<<<dim3(8, 8, 7), 256, 0, stream>>>(Mtmp, final_w, flag,
                                                          DThi, DTlo);
    bias1_kernel<<<256, 256, 0, stream>>>(s_l_w, s_a_w, s_v_w, out_b,
                                          s_l_b, s_a_b, s_v_b, flag, c0);
    bias2_kernel<<<256, 256, 0, stream>>>(c0, final_w, final_b, flag, d0);
    final_gemm_mfma_kernel<<<dim3(4, 192), 256, 0, stream>>>(Ohi, Olo, DThi, DTlo,
                                                             d0, flag, d_out);
}

// Round 17
// 218.069 us; speedup vs baseline: 1.0527x; 1.0527x over previous
//
#include <hip/hip_runtime.h>
#include <hip/hip_bf16.h>

#define E 256
#define H 8
#define HD 32
#define T 768
#define B 4
#define BH 32
// segments: L=[0,300), A=[300,550), V=[550,768)

typedef __attribute__((ext_vector_type(8))) short bf16x8;
typedef __attribute__((ext_vector_type(4))) float f32x4;

__device__ __forceinline__ float b2f(__hip_bfloat16 x) { return __bfloat162float(x); }

__device__ __forceinline__ unsigned short f2bf_u(float x) {
    __hip_bfloat16 h = __float2bfloat16(x);
    return *(unsigned short*)&h;
}
__device__ __forceinline__ float bfu2f(unsigned short u) {
    return __uint_as_float(((unsigned int)u) << 16);
}

// split fp32[8] -> bf16 hi + lo fragments
__device__ __forceinline__ void f8_split(const float* v, bf16x8& h, bf16x8& l) {
    #pragma unroll
    for (int e = 0; e < 8; ++e) {
        unsigned short hu = f2bf_u(v[e]);
        h[e] = (short)hu;
        l[e] = (short)f2bf_u(v[e] - bfu2f(hu));
    }
}

#define MFMA3(ACC, AH, AL, BH_, BL_)                                         \
    ACC = __builtin_amdgcn_mfma_f32_16x16x32_bf16(AH, BH_, ACC, 0, 0, 0);    \
    ACC = __builtin_amdgcn_mfma_f32_16x16x32_bf16(AH, BL_, ACC, 0, 0, 0);    \
    ACC = __builtin_amdgcn_mfma_f32_16x16x32_bf16(AL, BH_, ACC, 0, 0, 0);

// dtype-agnostic scalar load: f32 ? float : bf16
__device__ __forceinline__ float ldu(const void* p, size_t i, int f32) {
    if (f32) return ((const float*)p)[i];
    return b2f(((const __hip_bfloat16*)p)[i]);
}

// ---------------------------------------------------------------------------
// Kernel 0: input dtype detection (fp32 read as bf16 -> garbage exponents).
// ---------------------------------------------------------------------------
__global__ void detect_kernel(const unsigned short* __restrict__ q,
                              int* __restrict__ flag) {
    if (threadIdx.x == 0 && blockIdx.x == 0) {
        int f32 = 0;
        for (int i = 0; i < 256; ++i) {
            unsigned int bits = ((unsigned int)q[i]) << 16;
            float v = __uint_as_float(bits);
            if (!(v == v) || fabsf(v) > 1e4f) f32 = 1;
        }
        *flag = f32;
    }
}

// ---------------------------------------------------------------------------
// Kernel 0b (round-17): convert X (query/key/value) and in_proj_w to bf16
// hi/lo MFMA fragments, ONCE. Fragment-major:
//   XF[inp][rb 192][kb 8][lane 64][j 8], lane=(row&15)|((kg&3)<<4)
//   WF[sec 3][cb 16][kb 8][lane 64][j 8], lane=(col&15)|((kg&3)<<4)
// Lives in the O region (dead until attn runs — stream-order safe).
// ---------------------------------------------------------------------------
__global__ __launch_bounds__(256) void conv_kernel(
    const void* query, const void* key, const void* value, const void* w,
    const int* __restrict__ flag,
    unsigned short* __restrict__ XFh, unsigned short* __restrict__ XFl,
    unsigned short* __restrict__ WFh, unsigned short* __restrict__ WFl)
{
    int f32 = *flag;
    int item = blockIdx.x * 256 + threadIdx.x;
    if (item < 294912) {                       // X: 3 inputs x 3072 rows x 32 kg
        int inp = item / 98304;
        int rem = item % 98304;
        int row = rem >> 5, kg = rem & 31;
        const void* X = (inp == 0) ? query : (inp == 1) ? key : value;
        float v[8];
        if (f32) {
            const float4* p = (const float4*)((const float*)X +
                               (size_t)row * 256 + kg * 8);
            *(float4*)&v[0] = p[0];
            *(float4*)&v[4] = p[1];
        } else {
            #pragma unroll
            for (int j = 0; j < 8; ++j)
                v[j] = ldu(X, (size_t)row * 256 + kg * 8 + j, 0);
        }
        bf16x8 h, l;
        f8_split(v, h, l);
        int rb = row >> 4, kb = kg >> 2;
        int lane = (row & 15) | ((kg & 3) << 4);
        size_t idx = (((size_t)(inp * 192 + rb) * 8 + kb) * 64 + lane) * 8;
        *(bf16x8*)&XFh[idx] = h;
        *(bf16x8*)&XFl[idx] = l;
    } else if (item < 319488) {                // W: 768 rows x 32 kg
        int rem = item - 294912;
        int gc = rem >> 5, kg = rem & 31;
        float v[8];
        if (f32) {
            const float4* p = (const float4*)((const float*)w +
                               (size_t)gc * 256 + kg * 8);
            *(float4*)&v[0] = p[0];
            *(float4*)&v[4] = p[1];
        } else {
            #pragma unroll
            for (int j = 0; j < 8; ++j)
                v[j] = ldu(w, (size_t)gc * 256 + kg * 8 + j, 0);
        }
        bf16x8 h, l;
        f8_split(v, h, l);
        int sec = gc >> 8, c = gc & 255;
        int cb = c >> 4, kb = kg >> 2;
        int lane = (c & 15) | ((kg & 3) << 4);
        size_t idx = (((size_t)(sec * 16 + cb) * 8 + kb) * 64 + lane) * 8;
        *(bf16x8*)&WFh[idx] = h;
        *(bf16x8*)&WFl[idx] = l;
    }
}

// ---------------------------------------------------------------------------
// Kernel 1 (round-17): QKV projection via MFMA. Wave = one 16x16 tile,
// K=256 (8 kb x 3 split-MFMAs). Fragments straight from global (r13 pattern).
// Epilogue = r16's proven q/k/v store maps.
// ---------------------------------------------------------------------------
__global__ __launch_bounds__(256) void qkv_mfma_kernel(
    const unsigned short* __restrict__ XFh, const unsigned short* __restrict__ XFl,
    const unsigned short* __restrict__ WFh, const unsigned short* __restrict__ WFl,
    const void* bias, const int* __restrict__ flag,
    float* __restrict__ qws,
    unsigned short* __restrict__ KGh, unsigned short* __restrict__ KGl,
    unsigned short* __restrict__ VGh, unsigned short* __restrict__ VGl)
{
    int f32 = *flag;
    int bx = blockIdx.x;          // 0..11: sec=bx>>2, colgroup=bx&3
    int rb = blockIdx.y;          // 0..191 rowblk
    int sec = bx >> 2, cg = bx & 3;
    int w = threadIdx.x >> 6, lane = threadIdx.x & 63;
    int m = lane & 15, quad = lane >> 4;
    int cb = cg * 4 + w;          // colblk 0..15 within section

    const unsigned short* Ah = XFh + (((size_t)(sec * 192 + rb) * 8) * 64 + lane) * 8;
    const unsigned short* Al = XFl + (((size_t)(sec * 192 + rb) * 8) * 64 + lane) * 8;
    const unsigned short* Bh = WFh + (((size_t)(sec * 16 + cb) * 8) * 64 + lane) * 8;
    const unsigned short* Bl = WFl + (((size_t)(sec * 16 + cb) * 8) * 64 + lane) * 8;

    f32x4 acc = {};
    #pragma unroll
    for (int kb = 0; kb < 8; ++kb) {
        size_t off = (size_t)kb * 512;
        bf16x8 ah = *(const bf16x8*)(Ah + off);
        bf16x8 al = *(const bf16x8*)(Al + off);
        bf16x8 bh = *(const bf16x8*)(Bh + off);
        bf16x8 bl = *(const bf16x8*)(Bl + off);
        MFMA3(acc, ah, al, bh, bl)
    }

    int c_local = cb * 16 + m;                 // col within section
    float bv = ldu(bias, sec * 256 + c_local, f32);
    int h = c_local >> 5, hd = c_local & 31;

    if (sec == 0) {
        #pragma unroll
        for (int rr = 0; rr < 4; ++rr) {
            int row = rb * 16 + quad * 4 + rr;
            int t = row >> 2, b = row & 3;
            float val = (acc[rr] + bv) * 0.17677669529663687f;
            qws[((size_t)((b * H + h) * T + t)) * HD + hd] = val;
        }
    } else if (sec == 1) {
        #pragma unroll
        for (int rr = 0; rr < 4; ++rr) {
            int row = rb * 16 + quad * 4 + rr;
            int s = row >> 2, b = row & 3;
            int bh_ = b * 8 + h, ch = s >> 6;
            float val = acc[rr] + bv;
            unsigned short hu = f2bf_u(val);
            unsigned short lu = f2bf_u(val - bfu2f(hu));
            size_t bi = (((size_t)(bh_ * 12 + ch) * 4 + ((s >> 4) & 3)) * 64
                         + ((s & 15) | ((hd >> 3) << 4))) * 8 + (hd & 7);
            KGh[bi] = hu;
            KGl[bi] = lu;
        }
    } else {
        #pragma unroll
        for (int rr = 0; rr < 4; ++rr) {
            int row = rb * 16 + quad * 4 + rr;
            int s = row >> 2, b = row & 3;
            int bh_ = b * 8 + h, ch = s >> 6;
            float val = acc[rr] + bv;
            unsigned short hu = f2bf_u(val);
            unsigned short lu = f2bf_u(val - bfu2f(hu));
            int sl = s & 63, ks = sl >> 5, j = sl & 7, q3 = (sl >> 3) & 3;
            int hdb = hd >> 4;
            size_t bi = ((((size_t)(bh_ * 12 + ch) * 2 + hdb) * 2 + ks) * 64
                         + ((hd & 15) | (q3 << 4))) * 8 + j;
            VGh[bi] = hu;
            VGl[bi] = lu;
        }
    }
}

// ---------------------------------------------------------------------------
// Kernel 2 (proven round-16): MFMA attention, fragments from global,
// EPK double-buffered, PL aliases dead EPK.
// ---------------------------------------------------------------------------
__global__ __launch_bounds__(256) void attn_mfma_kernel(
    const float* __restrict__ qws,
    const unsigned short* __restrict__ KGh, const unsigned short* __restrict__ KGl,
    const unsigned short* __restrict__ VGh, const unsigned short* __restrict__ VGl,
    unsigned short* __restrict__ Ohi, unsigned short* __restrict__ Olo)
{
    int tile = blockIdx.x;       // 0..23
    int bh   = blockIdx.y;       // 0..31
    int t0 = tile * 32;
    int tid = threadIdx.x;
    int w = tid >> 6, lane = tid & 63;
    int m = lane & 15, quad = lane >> 4;
    int tb = w & 1, hdb = w >> 1;

    __shared__ __align__(16) unsigned int EPK[2][2048];
    __shared__ float SP[4][16][3];
    float* PL = (float*)&EPK[0][0];

    bf16x8 aqh, aql;
    {
        const float* qr = qws + ((size_t)bh * T + t0 + tb * 16 + m) * HD + quad * 8;
        float qv[8];
        *(float4*)&qv[0] = *(const float4*)qr;
        *(float4*)&qv[4] = *(const float4*)(qr + 4);
        f8_split(qv, aqh, aql);
    }

    f32x4 acc0 = {}, acc1 = {}, acc2 = {};
    float ss0[4] = {}, ss1[4] = {}, ss2[4] = {};

    for (int ch = 0; ch < 12; ++ch) {
        int base = ch * 64;
        int buf = ch & 1;
        #pragma unroll
        for (int sbi = 0; sbi < 2; ++sbi) {
            int sb = (w >> 1) * 2 + sbi;
            size_t kfi = (((size_t)(bh * 12 + ch) * 4 + sb) * 64 + lane) * 8;
            bf16x8 bkh = *(const bf16x8*)(KGh + kfi);
            bf16x8 bkl = *(const bf16x8*)(KGl + kfi);
            f32x4 d = {};
            MFMA3(d, aqh, aql, bkh, bkl)
            int s64 = sb * 16 + m;
            int sglob = base + s64;
            int ksw = s64 >> 5, qp = (s64 >> 3) & 3, jp = m & 7;
            unsigned int* eb = &EPK[buf][(tb * 2 + ksw) * 512 + jp];
            #pragma unroll
            for (int r = 0; r < 4; ++r) {
                float e = __expf(d[r]);
                if (sglob < 300) ss0[r] += e;
                else if (sglob < 550) ss1[r] += e;
                else ss2[r] += e;
                unsigned short hu = f2bf_u(e);
                unsigned short lu = f2bf_u(e - bfu2f(hu));
                eb[((quad * 4 + r) + 16 * qp) * 8] =
                    (unsigned int)hu | ((unsigned int)lu << 16);
            }
        }
        __syncthreads();

        #pragma unroll
        for (int ks = 0; ks < 2; ++ks) {
            const unsigned int* ep = &EPK[buf][((tb * 2 + ks) * 64 + lane) * 8];
            uint4 p0 = *(const uint4*)ep;
            uint4 p1 = *(const uint4*)(ep + 4);
            bf16x8 aeh, ael;
            aeh[0] = (short)(p0.x & 0xffff); ael[0] = (short)(p0.x >> 16);
            aeh[1] = (short)(p0.y & 0xffff); ael[1] = (short)(p0.y >> 16);
            aeh[2] = (short)(p0.z & 0xffff); ael[2] = (short)(p0.z >> 16);
            aeh[3] = (short)(p0.w & 0xffff); ael[3] = (short)(p0.w >> 16);
            aeh[4] = (short)(p1.x & 0xffff); ael[4] = (short)(p1.x >> 16);
            aeh[5] = (short)(p1.y & 0xffff); ael[5] = (short)(p1.y >> 16);
            aeh[6] = (short)(p1.z & 0xffff); ael[6] = (short)(p1.z >> 16);
            aeh[7] = (short)(p1.w & 0xffff); ael[7] = (short)(p1.w >> 16);
            size_t vfi = ((((size_t)(bh * 12 + ch) * 2 + hdb) * 2 + ks) * 64 + lane) * 8;
            bf16x8 bvh = *(const bf16x8*)(VGh + vfi);
            bf16x8 bvl = *(const bf16x8*)(VGl + vfi);
            int s_lo = base + ks * 32;
            if (s_lo + 32 <= 300) { MFMA3(acc0, aeh, ael, bvh, bvl) }
            else if (s_lo >= 300 && s_lo + 32 <= 550) { MFMA3(acc1, aeh, ael, bvh, bvl) }
            else if (s_lo >= 550) { MFMA3(acc2, aeh, ael, bvh, bvl) }
            else {
                int bnd = (s_lo < 300) ? 300 : 550;
                bf16x8 eha = aeh, ela = ael, ehb = aeh, elb = ael;
                #pragma unroll
                for (int j = 0; j < 8; ++j) {
                    int s = s_lo + quad * 8 + j;
                    if (s < bnd) { ehb[j] = 0; elb[j] = 0; }
                    else         { eha[j] = 0; ela[j] = 0; }
                }
                if (s_lo < 300) { MFMA3(acc0, eha, ela, bvh, bvl)
                                  MFMA3(acc1, ehb, elb, bvh, bvl) }
                else            { MFMA3(acc1, eha, ela, bvh, bvl)
                                  MFMA3(acc2, ehb, elb, bvh, bvl) }
            }
        }
    }

    #pragma unroll
    for (int sg = 0; sg < 3; ++sg)
        #pragma unroll
        for (int r = 0; r < 4; ++r) {
            float v = (sg == 0) ? ss0[r] : (sg == 1) ? ss1[r] : ss2[r];
            v += __shfl_down(v, 8, 16);
            v += __shfl_down(v, 4, 16);
            v += __shfl_down(v, 2, 16);
            v += __shfl_down(v, 1, 16);
            if (m == 0) SP[w][quad * 4 + r][sg] = v;
        }
    __syncthreads();

    #pragma unroll
    for (int r = 0; r < 4; ++r) {
        int t32 = tb * 16 + quad * 4 + r;
        int hd = hdb * 16 + m;
        PL[0 * 1152 + t32 * 36 + hd] = acc0[r];
        PL[1 * 1152 + t32 * 36 + hd] = acc1[r];
        PL[2 * 1152 + t32 * 36 + hd] = acc2[r];
    }
    __syncthreads();

    int tt = tid >> 3, q4 = tid & 7;
    float Pv[3][4];
    #pragma unroll
    for (int sg = 0; sg < 3; ++sg) {
        const float4 p = *(const float4*)&PL[sg * 1152 + tt * 36 + q4 * 4];
        Pv[sg][0] = p.x; Pv[sg][1] = p.y; Pv[sg][2] = p.z; Pv[sg][3] = p.w;
    }
    int tbe = tt >> 4, t16 = tt & 15;
    float S0 = SP[tbe][t16][0] + SP[tbe + 2][t16][0];
    float S1 = SP[tbe][t16][1] + SP[tbe + 2][t16][1];
    float S2 = SP[tbe][t16][2] + SP[tbe + 2][t16][2];

    int t_glob = t0 + tt;
    int g = (t_glob < 300) ? 0 : (t_glob < 550 ? 1 : 2);
    int b_ = bh >> 3, h_ = bh & 7;
    int row = t_glob * B + b_;
    int lslot = (row & 15) + ((q4 >> 1) << 4);
    int j0 = (q4 & 1) * 4;
    size_t fbase = (((size_t)(row >> 4) * 56 + h_) * 64 + lslot) * 8 + j0;
    const int masks[7] = {7, 3, 5, 6, 1, 2, 4};
    #pragma unroll
    for (int i = 0; i < 7; ++i) {
        int mm = masks[i];
        float n0 = 0.f, n1 = 0.f, n2 = 0.f, n3 = 0.f, den = 0.f;
        if (mm & 1) { n0 += Pv[0][0]; n1 += Pv[0][1]; n2 += Pv[0][2]; n3 += Pv[0][3]; den += S0; }
        if (mm & 2) { n0 += Pv[1][0]; n1 += Pv[1][1]; n2 += Pv[1][2]; n3 += Pv[1][3]; den += S1; }
        if (mm & 4) { n0 += Pv[2][0]; n1 += Pv[2][1]; n2 += Pv[2][2]; n3 += Pv[2][3]; den += S2; }
        float r = 1.f / den;
        int live = (mm >> g) & 1;
        float o[4];
        o[0] = live ? n0 * r : 0.f;
        o[1] = live ? n1 * r : 0.f;
        o[2] = live ? n2 * r : 0.f;
        o[3] = live ? n3 * r : 0.f;
        ushort4 hi4, lo4;
        unsigned short* hp = (unsigned short*)&hi4;
        unsigned short* lp = (unsigned short*)&lo4;
        #pragma unroll
        for (int j = 0; j < 4; ++j) {
            unsigned short hu = f2bf_u(o[j]);
            hp[j] = hu;
            lp[j] = f2bf_u(o[j] - bfu2f(hu));
        }
        size_t addr = fbase + (size_t)i * (8 * 64 * 8);
        *(ushort4*)&Ohi[addr] = hi4;
        *(ushort4*)&Olo[addr] = lo4;
    }
}

// ---------------------------------------------------------------------------
// Weight combination: D_i = (final_w @ G_i @ out_w[i])^T stacked as (1792,256).
// ---------------------------------------------------------------------------
__device__ __forceinline__ float gsum_load(int i, int r2, int r,
                                           const void* sl, const void* sa,
                                           const void* sv, int f32)
{
    size_t base = (size_t)r2 * 1024;
    switch (i) {
        case 0: return ldu(sl, base + r, f32) + ldu(sa, base + r, f32) + ldu(sv, base + r, f32);
        case 1: return ldu(sl, base + 256 + r, f32) + ldu(sa, base + 256 + r, f32);
        case 2: return ldu(sl, base + 512 + r, f32) + ldu(sv, base + 256 + r, f32);
        case 3: return ldu(sa, base + 512 + r, f32) + ldu(sv, base + 512 + r, f32);
        case 4: return ldu(sl, base + 768 + r, f32);
        case 5: return ldu(sa, base + 768 + r, f32);
        default: return ldu(sv, base + 768 + r, f32);
    }
}

// Mtmp_i = G_i @ out_w[i]    (proven round-2)
__global__ __launch_bounds__(256) void wcomb1_kernel(
    const void* sl, const void* sa, const void* sv, const void* outw,
    const int* __restrict__ flag, float* __restrict__ Mtmp)
{
    int f32 = *flag;
    int bid = blockIdx.x;
    int i = bid >> 8, r2 = bid & 255;
    int c = threadIdx.x;
    __shared__ float g[256];
    g[c] = gsum_load(i, r2, c, sl, sa, sv, f32);
    __syncthreads();
    float acc = 0.f;
    for (int r = 0; r < 256; ++r)
        acc += g[r] * ldu(outw, (size_t)i * 65536 + r * 256 + c, f32);
    Mtmp[(size_t)i * 65536 + r2 * 256 + c] = acc;
}

// DT hi/lo fragment-major (proven round-15: 32x32 tiles, grid (8,8,7)).
__global__ __launch_bounds__(256) void wcomb2_gemm_kernel(
    const float* __restrict__ Mtmp, const void* finalw,
    const int* __restrict__ flag,
    unsigned short* __restrict__ DThi, unsigned short* __restrict__ DTlo)
{
    int f32 = *flag;
    int bx = blockIdx.x;   // e tile 0..7
    int by = blockIdx.y;   // c tile 0..7
    int i  = blockIdx.z;   // branch 0..6
    int tid = threadIdx.x;
    int tx = tid & 15, ty = tid >> 4;
    int colbase = bx * 32, rowbase = by * 32;
    __shared__ __align__(16) float AsT[32][34];
    __shared__ __align__(16) float Bs[32][34];
    float acc[2][2] = {};

    for (int kb = 0; kb < 8; ++kb) {
        __syncthreads();
        #pragma unroll
        for (int l = 0; l < 4; ++l) {
            int idx = l * 256 + tid;
            int c = idx & 31, kk = idx >> 5;
            AsT[kk][c] = Mtmp[(size_t)i * 65536 + (kb * 32 + kk) * 256 + rowbase + c];
            int k2 = idx & 31, n = idx >> 5;
            Bs[k2][n] = ldu(finalw, (size_t)(colbase + n) * 256 + kb * 32 + k2, f32);
        }
        __syncthreads();
        #pragma unroll 8
        for (int kk = 0; kk < 32; ++kk) {
            const float2 av = *(const float2*)&AsT[kk][ty * 2];
            const float2 bv = *(const float2*)&Bs[kk][tx * 2];
            acc[0][0] += av.x * bv.x; acc[0][1] += av.x * bv.y;
            acc[1][0] += av.y * bv.x; acc[1][1] += av.y * bv.y;
        }
    }
    #pragma unroll
    for (int u = 0; u < 2; ++u)
        #pragma unroll
        for (int v = 0; v < 2; ++v) {
            int c = rowbase + ty * 2 + u, e = colbase + tx * 2 + v;
            float a = acc[u][v];
            unsigned short hu = f2bf_u(a);
            size_t fidx = (((size_t)(e >> 4) * 56 + i * 8 + (c >> 5)) * 64
                           + (e & 15) + (((c >> 3) & 3) << 4)) * 8 + (c & 7);
            DThi[fidx] = hu;
            DTlo[fidx] = f2bf_u(a - bfu2f(hu));
        }
}

// ---------------------------------------------------------------------------
// Bias path (proven round-5). c0 ALIASES Mtmp (dead after wcomb2).
// ---------------------------------------------------------------------------
__global__ __launch_bounds__(256) void bias1_kernel(
    const void* sl, const void* sa, const void* sv, const void* outb,
    const void* slb, const void* sab, const void* svb,
    const int* __restrict__ flag, float* __restrict__ c0)
{
    int f32 = *flag;
    int r2 = blockIdx.x, m = threadIdx.x;
    __shared__ float red[256];
    float acc = 0.f;
    #pragma unroll
    for (int i = 0; i < 7; ++i)
        acc += ldu(outb, i * 256 + m, f32) * gsum_load(i, r2, m, sl, sa, sv, f32);
    red[m] = acc;
    __syncthreads();
    for (int s = 128; s > 0; s >>= 1) {
        if (m < s) red[m] += red[m + s];
        __syncthreads();
    }
    if (m == 0)
        c0[r2] = red[0] + ldu(slb, r2, f32) + ldu(sab, r2, f32) + ldu(svb, r2, f32);
}

__global__ __launch_bounds__(256) void bias2_kernel(
    const float* __restrict__ c0, const void* finalw, const void* finalb,
    const int* __restrict__ flag, float* __restrict__ d0)
{
    int f32 = *flag;
    int e = blockIdx.x, r = threadIdx.x;
    __shared__ float red[256];
    red[r] = c0[r] * ldu(finalw, (size_t)e * 256 + r, f32);
    __syncthreads();
    for (int s = 128; s > 0; s >>= 1) {
        if (r < s) red[r] += red[r + s];
        __syncthreads();
    }
    if (r == 0)
        d0[e] = red[0] + ldu(finalb, e, f32);
}

// ---------------------------------------------------------------------------
// Kernel 4 (proven round-13, MFMA + fragment-major): result = O@Dstack + d0.
// ---------------------------------------------------------------------------
__global__ __launch_bounds__(256) void final_gemm_mfma_kernel(
    const unsigned short* __restrict__ Ohi, const unsigned short* __restrict__ Olo,
    const unsigned short* __restrict__ DThi, const unsigned short* __restrict__ DTlo,
    const float* __restrict__ d0, const int* __restrict__ flag,
    void* __restrict__ outv)
{
    int f32 = *flag;
    int bx = blockIdx.x;
    int by = blockIdx.y;
    int w  = threadIdx.x >> 6;
    int lane = threadIdx.x & 63;
    int m = lane & 15, quad = lane >> 4;
    int R0 = by * 16, C0 = bx * 64 + w * 16;

    int t0 = R0 >> 2, t1 = (R0 + 15) >> 2;
    int g0 = (t0 < 300) ? 0 : (t0 < 550 ? 1 : 2);
    int g1 = (t1 < 300) ? 0 : (t1 < 550 ? 1 : 2);
    int activeset = (1 << g0) | (1 << g1);
    const int masks[7] = {7, 3, 5, 6, 1, 2, 4};

    const unsigned short* Abase_h = Ohi + (size_t)by * 56 * 512 + lane * 8;
    const unsigned short* Abase_l = Olo + (size_t)by * 56 * 512 + lane * 8;
    const unsigned short* Bbase_h = DThi + (size_t)(bx * 4 + w) * 56 * 512 + lane * 8;
    const unsigned short* Bbase_l = DTlo + (size_t)(bx * 4 + w) * 56 * 512 + lane * 8;

    f32x4 acc = {};
    for (int i = 0; i < 7; ++i) {
        if (!(masks[i] & activeset)) continue;
        #pragma unroll
        for (int kb = 0; kb < 8; ++kb) {
            size_t off = (size_t)(i * 8 + kb) * 512;
            bf16x8 ah = *(const bf16x8*)(Abase_h + off);
            bf16x8 al = *(const bf16x8*)(Abase_l + off);
            bf16x8 bh = *(const bf16x8*)(Bbase_h + off);
            bf16x8 bl = *(const bf16x8*)(Bbase_l + off);
            acc = __builtin_amdgcn_mfma_f32_16x16x32_bf16(ah, bh, acc, 0, 0, 0);
            acc = __builtin_amdgcn_mfma_f32_16x16x32_bf16(ah, bl, acc, 0, 0, 0);
            acc = __builtin_amdgcn_mfma_f32_16x16x32_bf16(al, bh, acc, 0, 0, 0);
        }
    }
    float dv = d0[C0 + m];
    #pragma unroll
    for (int r = 0; r < 4; ++r) {
        int row = R0 + quad * 4 + r;
        int col = C0 + m;
        float val = acc[r] + dv;
        if (f32) ((float*)outv)[(size_t)row * 256 + col] = val;
        else ((__hip_bfloat16*)outv)[(size_t)row * 256 + col] = __float2bfloat16(val);
    }
}

// ---------------------------------------------------------------------------
extern "C" void kernel_launch(void* const* d_in, const int* in_sizes, int n_in,
                              void* d_out, int out_size, void* d_ws, size_t ws_size,
                              hipStream_t stream) {
    const void* query     = d_in[0];
    const void* key       = d_in[1];
    const void* value     = d_in[2];
    const void* in_proj_w = d_in[3];
    const void* in_proj_b = d_in[4];
    const void* out_w     = d_in[5];
    const void* out_b     = d_in[6];
    const void* s_l_w     = d_in[7];
    const void* s_l_b     = d_in[8];
    const void* s_a_w     = d_in[9];
    const void* s_a_b     = d_in[10];
    const void* s_v_w     = d_in[11];
    const void* s_v_b     = d_in[12];
    const void* final_w   = d_in[13];
    const void* final_b   = d_in[14];

    float* ws     = (float*)d_ws;
    float* qws    = ws;                 //   786432 f (q fp32)
    unsigned short* KGh = (unsigned short*)(ws + 786432);
    unsigned short* KGl = KGh + 786432;
    unsigned short* VGh = (unsigned short*)(ws + 1572864);
    unsigned short* VGl = VGh + 786432;
    // O region [2359296, 7864320): Ohi/Olo for attn+final; ALSO aliased by
    // XF/WF conversion buffers (dead before attn writes O — stream order).
    unsigned short* Ohi = (unsigned short*)(ws + 2359296);   // 5505024 bf16
    unsigned short* Olo = (unsigned short*)(ws + 5111808);   // 5505024 bf16
    unsigned short* XFh = (unsigned short*)(ws + 2359296);   // 2359296 bf16
    unsigned short* XFl = XFh + 2359296;                     // 2359296 bf16
    unsigned short* WFh = XFl + 2359296;                     //  196608 bf16
    unsigned short* WFl = WFh + 196608;                      //  196608 bf16
    float* Mtmp   = ws + 7864320;       //   458752 f
    unsigned short* DThi = (unsigned short*)(ws + 8323072);  // 458752 bf16
    unsigned short* DTlo = (unsigned short*)(ws + 8552448);  // 458752 bf16
    float* d0     = ws + 8781824;       //      256 f
    int*   flag   = (int*)(ws + 8782080);  // 1 int — proven footprint HIGH-WATER
    float* c0     = Mtmp;               // ALIAS: Mtmp dead after wcomb2

    detect_kernel<<<1, 64, 0, stream>>>((const unsigned short*)query, flag);
    conv_kernel<<<1248, 256, 0, stream>>>(query, key, value, in_proj_w, flag,
                                          XFh, XFl, WFh, WFl);
    qkv_mfma_kernel<<<dim3(12, 192), 256, 0, stream>>>(XFh, XFl, WFh, WFl,
                                                       in_proj_b, flag, qws,
                                                       KGh, KGl, VGh, VGl);
    wcomb1_kernel<<<7 * 256, 256, 0, stream>>>(s_l_w, s_a_w, s_v_w, out_w, flag, Mtmp);
    attn_mfma_kernel<<<dim3(24, 32), 256, 0, stream>>>(qws, KGh, KGl, VGh, VGl,
                                                       Ohi, Olo);
    wcomb2_gemm_kernel<<<dim3(8, 8, 7), 256, 0, stream>>>(Mtmp, final_w, flag,
                                                          DThi, DTlo);
    bias1_kernel<<<256, 256, 0, stream>>>(s_l_w, s_a_w, s_v_w, out_b,
                                          s_l_b, s_a_b, s_v_b, flag, c0);
    bias2_kernel<<<256, 256, 0, stream>>>(c0, final_w, final_b, flag, d0);
    final_gemm_mfma_kernel<<<dim3(4, 192), 256, 0, stream>>>(Ohi, Olo, DThi, DTlo,
                                                             d0, flag, d_out);
}

// Round 18
// 201.381 us; speedup vs baseline: 1.1399x; 1.0829x over previous
//
#include <hip/hip_runtime.h>
#include <hip/hip_bf16.h>

#define E 256
#define H 8
#define HD 32
#define T 768
#define B 4
#define BH 32
// segments: L=[0,300), A=[300,550), V=[550,768)

typedef __attribute__((ext_vector_type(8))) short bf16x8;
typedef __attribute__((ext_vector_type(4))) float f32x4;

__device__ __forceinline__ float b2f(__hip_bfloat16 x) { return __bfloat162float(x); }

__device__ __forceinline__ unsigned short f2bf_u(float x) {
    __hip_bfloat16 h = __float2bfloat16(x);
    return *(unsigned short*)&h;
}
__device__ __forceinline__ float bfu2f(unsigned short u) {
    return __uint_as_float(((unsigned int)u) << 16);
}

// split fp32[8] -> bf16 hi + lo fragments
__device__ __forceinline__ void f8_split(const float* v, bf16x8& h, bf16x8& l) {
    #pragma unroll
    for (int e = 0; e < 8; ++e) {
        unsigned short hu = f2bf_u(v[e]);
        h[e] = (short)hu;
        l[e] = (short)f2bf_u(v[e] - bfu2f(hu));
    }
}

#define MFMA3(ACC, AH, AL, BH_, BL_)                                         \
    ACC = __builtin_amdgcn_mfma_f32_16x16x32_bf16(AH, BH_, ACC, 0, 0, 0);    \
    ACC = __builtin_amdgcn_mfma_f32_16x16x32_bf16(AH, BL_, ACC, 0, 0, 0);    \
    ACC = __builtin_amdgcn_mfma_f32_16x16x32_bf16(AL, BH_, ACC, 0, 0, 0);

// dtype-agnostic scalar load: f32 ? float : bf16
__device__ __forceinline__ float ldu(const void* p, size_t i, int f32) {
    if (f32) return ((const float*)p)[i];
    return b2f(((const __hip_bfloat16*)p)[i]);
}

// G_i row loader (branch-summed s_*_w blocks)
__device__ __forceinline__ float gsum_load(int i, int r2, int r,
                                           const void* sl, const void* sa,
                                           const void* sv, int f32)
{
    size_t base = (size_t)r2 * 1024;
    switch (i) {
        case 0: return ldu(sl, base + r, f32) + ldu(sa, base + r, f32) + ldu(sv, base + r, f32);
        case 1: return ldu(sl, base + 256 + r, f32) + ldu(sa, base + 256 + r, f32);
        case 2: return ldu(sl, base + 512 + r, f32) + ldu(sv, base + 256 + r, f32);
        case 3: return ldu(sa, base + 512 + r, f32) + ldu(sv, base + 512 + r, f32);
        case 4: return ldu(sl, base + 768 + r, f32);
        case 5: return ldu(sa, base + 768 + r, f32);
        default: return ldu(sv, base + 768 + r, f32);
    }
}

// ---------------------------------------------------------------------------
// Kernel 0: input dtype detection (fp32 read as bf16 -> garbage exponents).
// ---------------------------------------------------------------------------
__global__ void detect_kernel(const unsigned short* __restrict__ q,
                              int* __restrict__ flag) {
    if (threadIdx.x == 0 && blockIdx.x == 0) {
        int f32 = 0;
        for (int i = 0; i < 256; ++i) {
            unsigned int bits = ((unsigned int)q[i]) << 16;
            float v = __uint_as_float(bits);
            if (!(v == v) || fabsf(v) > 1e4f) f32 = 1;
        }
        *flag = f32;
    }
}

// ---------------------------------------------------------------------------
// Kernel 0b (r17 + r18): one-shot conversion to bf16 hi/lo MFMA fragments.
//   XF[inp][rb 192][kb 8][lane][8]   (A: rows of q/k/v inputs)
//   WF[sec 3][cb 16][kb 8][lane][8]  (B: in_proj_w rows)
//   GF[i 7][rb 16][kb 8][lane][8]    (A: G_i rows, r18)
//   OWF[i 7][cb 16][kb 8][lane][8]   (B: out_w^T cols, r18)
// All live in the O-alias region (dead until attn; users run before attn).
// ---------------------------------------------------------------------------
__global__ __launch_bounds__(256) void conv_kernel(
    const void* query, const void* key, const void* value, const void* w,
    const void* sl, const void* sa, const void* sv, const void* outw,
    const int* __restrict__ flag,
    unsigned short* __restrict__ XFh, unsigned short* __restrict__ XFl,
    unsigned short* __restrict__ WFh, unsigned short* __restrict__ WFl,
    unsigned short* __restrict__ GFh, unsigned short* __restrict__ GFl,
    unsigned short* __restrict__ OWFh, unsigned short* __restrict__ OWFl)
{
    int f32 = *flag;
    int item = blockIdx.x * 256 + threadIdx.x;
    if (item < 294912) {                       // X: 3 inputs x 3072 rows x 32 kg
        int inp = item / 98304;
        int rem = item % 98304;
        int row = rem >> 5, kg = rem & 31;
        const void* X = (inp == 0) ? query : (inp == 1) ? key : value;
        float v[8];
        if (f32) {
            const float4* p = (const float4*)((const float*)X +
                               (size_t)row * 256 + kg * 8);
            *(float4*)&v[0] = p[0];
            *(float4*)&v[4] = p[1];
        } else {
            #pragma unroll
            for (int j = 0; j < 8; ++j)
                v[j] = ldu(X, (size_t)row * 256 + kg * 8 + j, 0);
        }
        bf16x8 h, l;
        f8_split(v, h, l);
        int rb = row >> 4, kb = kg >> 2;
        int lane = (row & 15) | ((kg & 3) << 4);
        size_t idx = (((size_t)(inp * 192 + rb) * 8 + kb) * 64 + lane) * 8;
        *(bf16x8*)&XFh[idx] = h;
        *(bf16x8*)&XFl[idx] = l;
    } else if (item < 319488) {                // W: 768 rows x 32 kg
        int rem = item - 294912;
        int gc = rem >> 5, kg = rem & 31;
        float v[8];
        if (f32) {
            const float4* p = (const float4*)((const float*)w +
                               (size_t)gc * 256 + kg * 8);
            *(float4*)&v[0] = p[0];
            *(float4*)&v[4] = p[1];
        } else {
            #pragma unroll
            for (int j = 0; j < 8; ++j)
                v[j] = ldu(w, (size_t)gc * 256 + kg * 8 + j, 0);
        }
        bf16x8 h, l;
        f8_split(v, h, l);
        int sec = gc >> 8, c = gc & 255;
        int cb = c >> 4, kb = kg >> 2;
        int lane = (c & 15) | ((kg & 3) << 4);
        size_t idx = (((size_t)(sec * 16 + cb) * 8 + kb) * 64 + lane) * 8;
        *(bf16x8*)&WFh[idx] = h;
        *(bf16x8*)&WFl[idx] = l;
    } else if (item < 376832) {                // G: 7 x 256 r2 x 32 kg
        int rem = item - 319488;
        int i = rem >> 13;
        int rest = rem & 8191;
        int r2 = rest >> 5, kg = rest & 31;
        float v[8];
        #pragma unroll
        for (int j = 0; j < 8; ++j)
            v[j] = gsum_load(i, r2, kg * 8 + j, sl, sa, sv, f32);
        bf16x8 h, l;
        f8_split(v, h, l);
        int rb = r2 >> 4, kb = kg >> 2;
        int lane = (r2 & 15) | ((kg & 3) << 4);
        size_t idx = (((size_t)(i * 16 + rb) * 8 + kb) * 64 + lane) * 8;
        *(bf16x8*)&GFh[idx] = h;
        *(bf16x8*)&GFl[idx] = l;
    } else if (item < 434176) {                // OW^T: 7 x 32 kg x 256 c
        int rem = item - 376832;
        int i = rem >> 13;
        int rest = rem & 8191;
        int kg = rest >> 8, c = rest & 255;
        float v[8];
        #pragma unroll
        for (int j = 0; j < 8; ++j)
            v[j] = ldu(outw, (size_t)i * 65536 + (kg * 8 + j) * 256 + c, f32);
        bf16x8 h, l;
        f8_split(v, h, l);
        int cb = c >> 4, kb = kg >> 2;
        int lane = (c & 15) | ((kg & 3) << 4);
        size_t idx = (((size_t)(i * 16 + cb) * 8 + kb) * 64 + lane) * 8;
        *(bf16x8*)&OWFh[idx] = h;
        *(bf16x8*)&OWFl[idx] = l;
    }
}

// ---------------------------------------------------------------------------
// Kernel 1 (proven round-17): QKV projection via MFMA.
// ---------------------------------------------------------------------------
__global__ __launch_bounds__(256) void qkv_mfma_kernel(
    const unsigned short* __restrict__ XFh, const unsigned short* __restrict__ XFl,
    const unsigned short* __restrict__ WFh, const unsigned short* __restrict__ WFl,
    const void* bias, const int* __restrict__ flag,
    float* __restrict__ qws,
    unsigned short* __restrict__ KGh, unsigned short* __restrict__ KGl,
    unsigned short* __restrict__ VGh, unsigned short* __restrict__ VGl)
{
    int f32 = *flag;
    int bx = blockIdx.x;          // 0..11: sec=bx>>2, colgroup=bx&3
    int rb = blockIdx.y;          // 0..191 rowblk
    int sec = bx >> 2, cg = bx & 3;
    int w = threadIdx.x >> 6, lane = threadIdx.x & 63;
    int m = lane & 15, quad = lane >> 4;
    int cb = cg * 4 + w;          // colblk 0..15 within section

    const unsigned short* Ah = XFh + (((size_t)(sec * 192 + rb) * 8) * 64 + lane) * 8;
    const unsigned short* Al = XFl + (((size_t)(sec * 192 + rb) * 8) * 64 + lane) * 8;
    const unsigned short* Bh = WFh + (((size_t)(sec * 16 + cb) * 8) * 64 + lane) * 8;
    const unsigned short* Bl = WFl + (((size_t)(sec * 16 + cb) * 8) * 64 + lane) * 8;

    f32x4 acc = {};
    #pragma unroll
    for (int kb = 0; kb < 8; ++kb) {
        size_t off = (size_t)kb * 512;
        bf16x8 ah = *(const bf16x8*)(Ah + off);
        bf16x8 al = *(const bf16x8*)(Al + off);
        bf16x8 bh = *(const bf16x8*)(Bh + off);
        bf16x8 bl = *(const bf16x8*)(Bl + off);
        MFMA3(acc, ah, al, bh, bl)
    }

    int c_local = cb * 16 + m;                 // col within section
    float bv = ldu(bias, sec * 256 + c_local, f32);
    int h = c_local >> 5, hd = c_local & 31;

    if (sec == 0) {
        #pragma unroll
        for (int rr = 0; rr < 4; ++rr) {
            int row = rb * 16 + quad * 4 + rr;
            int t = row >> 2, b = row & 3;
            float val = (acc[rr] + bv) * 0.17677669529663687f;
            qws[((size_t)((b * H + h) * T + t)) * HD + hd] = val;
        }
    } else if (sec == 1) {
        #pragma unroll
        for (int rr = 0; rr < 4; ++rr) {
            int row = rb * 16 + quad * 4 + rr;
            int s = row >> 2, b = row & 3;
            int bh_ = b * 8 + h, ch = s >> 6;
            float val = acc[rr] + bv;
            unsigned short hu = f2bf_u(val);
            unsigned short lu = f2bf_u(val - bfu2f(hu));
            size_t bi = (((size_t)(bh_ * 12 + ch) * 4 + ((s >> 4) & 3)) * 64
                         + ((s & 15) | ((hd >> 3) << 4))) * 8 + (hd & 7);
            KGh[bi] = hu;
            KGl[bi] = lu;
        }
    } else {
        #pragma unroll
        for (int rr = 0; rr < 4; ++rr) {
            int row = rb * 16 + quad * 4 + rr;
            int s = row >> 2, b = row & 3;
            int bh_ = b * 8 + h, ch = s >> 6;
            float val = acc[rr] + bv;
            unsigned short hu = f2bf_u(val);
            unsigned short lu = f2bf_u(val - bfu2f(hu));
            int sl = s & 63, ks = sl >> 5, j = sl & 7, q3 = (sl >> 3) & 3;
            int hdb = hd >> 4;
            size_t bi = ((((size_t)(bh_ * 12 + ch) * 2 + hdb) * 2 + ks) * 64
                         + ((hd & 15) | (q3 << 4))) * 8 + j;
            VGh[bi] = hu;
            VGl[bi] = lu;
        }
    }
}

// ---------------------------------------------------------------------------
// Kernel 1b (NEW round-18): Mtmp_i = G_i @ out_w[i] via MFMA.
// Wave = one 16x16 tile, K=256 (8 kb x MFMA3). Grid (4,16,7) = 448 blocks.
// ---------------------------------------------------------------------------
__global__ __launch_bounds__(256) void wcomb1_mfma_kernel(
    const unsigned short* __restrict__ GFh, const unsigned short* __restrict__ GFl,
    const unsigned short* __restrict__ OWFh, const unsigned short* __restrict__ OWFl,
    float* __restrict__ Mtmp)
{
    int cgrp = blockIdx.x;        // 0..3
    int rb   = blockIdx.y;        // 0..15 (r2 block)
    int i    = blockIdx.z;        // branch 0..6
    int w = threadIdx.x >> 6, lane = threadIdx.x & 63;
    int m = lane & 15, quad = lane >> 4;
    int cb = cgrp * 4 + w;        // c block 0..15

    const unsigned short* Ah = GFh + (((size_t)(i * 16 + rb) * 8) * 64 + lane) * 8;
    const unsigned short* Al = GFl + (((size_t)(i * 16 + rb) * 8) * 64 + lane) * 8;
    const unsigned short* Bh = OWFh + (((size_t)(i * 16 + cb) * 8) * 64 + lane) * 8;
    const unsigned short* Bl = OWFl + (((size_t)(i * 16 + cb) * 8) * 64 + lane) * 8;

    f32x4 acc = {};
    #pragma unroll
    for (int kb = 0; kb < 8; ++kb) {
        size_t off = (size_t)kb * 512;
        bf16x8 ah = *(const bf16x8*)(Ah + off);
        bf16x8 al = *(const bf16x8*)(Al + off);
        bf16x8 bh = *(const bf16x8*)(Bh + off);
        bf16x8 bl = *(const bf16x8*)(Bl + off);
        MFMA3(acc, ah, al, bh, bl)
    }
    #pragma unroll
    for (int rr = 0; rr < 4; ++rr) {
        int r2 = rb * 16 + quad * 4 + rr;
        Mtmp[(size_t)i * 65536 + r2 * 256 + cb * 16 + m] = acc[rr];
    }
}

// ---------------------------------------------------------------------------
// Kernel 2 (proven round-16): MFMA attention.
// ---------------------------------------------------------------------------
__global__ __launch_bounds__(256) void attn_mfma_kernel(
    const float* __restrict__ qws,
    const unsigned short* __restrict__ KGh, const unsigned short* __restrict__ KGl,
    const unsigned short* __restrict__ VGh, const unsigned short* __restrict__ VGl,
    unsigned short* __restrict__ Ohi, unsigned short* __restrict__ Olo)
{
    int tile = blockIdx.x;       // 0..23
    int bh   = blockIdx.y;       // 0..31
    int t0 = tile * 32;
    int tid = threadIdx.x;
    int w = tid >> 6, lane = tid & 63;
    int m = lane & 15, quad = lane >> 4;
    int tb = w & 1, hdb = w >> 1;

    __shared__ __align__(16) unsigned int EPK[2][2048];
    __shared__ float SP[4][16][3];
    float* PL = (float*)&EPK[0][0];

    bf16x8 aqh, aql;
    {
        const float* qr = qws + ((size_t)bh * T + t0 + tb * 16 + m) * HD + quad * 8;
        float qv[8];
        *(float4*)&qv[0] = *(const float4*)qr;
        *(float4*)&qv[4] = *(const float4*)(qr + 4);
        f8_split(qv, aqh, aql);
    }

    f32x4 acc0 = {}, acc1 = {}, acc2 = {};
    float ss0[4] = {}, ss1[4] = {}, ss2[4] = {};

    for (int ch = 0; ch < 12; ++ch) {
        int base = ch * 64;
        int buf = ch & 1;
        #pragma unroll
        for (int sbi = 0; sbi < 2; ++sbi) {
            int sb = (w >> 1) * 2 + sbi;
            size_t kfi = (((size_t)(bh * 12 + ch) * 4 + sb) * 64 + lane) * 8;
            bf16x8 bkh = *(const bf16x8*)(KGh + kfi);
            bf16x8 bkl = *(const bf16x8*)(KGl + kfi);
            f32x4 d = {};
            MFMA3(d, aqh, aql, bkh, bkl)
            int s64 = sb * 16 + m;
            int sglob = base + s64;
            int ksw = s64 >> 5, qp = (s64 >> 3) & 3, jp = m & 7;
            unsigned int* eb = &EPK[buf][(tb * 2 + ksw) * 512 + jp];
            #pragma unroll
            for (int r = 0; r < 4; ++r) {
                float e = __expf(d[r]);
                if (sglob < 300) ss0[r] += e;
                else if (sglob < 550) ss1[r] += e;
                else ss2[r] += e;
                unsigned short hu = f2bf_u(e);
                unsigned short lu = f2bf_u(e - bfu2f(hu));
                eb[((quad * 4 + r) + 16 * qp) * 8] =
                    (unsigned int)hu | ((unsigned int)lu << 16);
            }
        }
        __syncthreads();

        #pragma unroll
        for (int ks = 0; ks < 2; ++ks) {
            const unsigned int* ep = &EPK[buf][((tb * 2 + ks) * 64 + lane) * 8];
            uint4 p0 = *(const uint4*)ep;
            uint4 p1 = *(const uint4*)(ep + 4);
            bf16x8 aeh, ael;
            aeh[0] = (short)(p0.x & 0xffff); ael[0] = (short)(p0.x >> 16);
            aeh[1] = (short)(p0.y & 0xffff); ael[1] = (short)(p0.y >> 16);
            aeh[2] = (short)(p0.z & 0xffff); ael[2] = (short)(p0.z >> 16);
            aeh[3] = (short)(p0.w & 0xffff); ael[3] = (short)(p0.w >> 16);
            aeh[4] = (short)(p1.x & 0xffff); ael[4] = (short)(p1.x >> 16);
            aeh[5] = (short)(p1.y & 0xffff); ael[5] = (short)(p1.y >> 16);
            aeh[6] = (short)(p1.z & 0xffff); ael[6] = (short)(p1.z >> 16);
            aeh[7] = (short)(p1.w & 0xffff); ael[7] = (short)(p1.w >> 16);
            size_t vfi = ((((size_t)(bh * 12 + ch) * 2 + hdb) * 2 + ks) * 64 + lane) * 8;
            bf16x8 bvh = *(const bf16x8*)(VGh + vfi);
            bf16x8 bvl = *(const bf16x8*)(VGl + vfi);
            int s_lo = base + ks * 32;
            if (s_lo + 32 <= 300) { MFMA3(acc0, aeh, ael, bvh, bvl) }
            else if (s_lo >= 300 && s_lo + 32 <= 550) { MFMA3(acc1, aeh, ael, bvh, bvl) }
            else if (s_lo >= 550) { MFMA3(acc2, aeh, ael, bvh, bvl) }
            else {
                int bnd = (s_lo < 300) ? 300 : 550;
                bf16x8 eha = aeh, ela = ael, ehb = aeh, elb = ael;
                #pragma unroll
                for (int j = 0; j < 8; ++j) {
                    int s = s_lo + quad * 8 + j;
                    if (s < bnd) { ehb[j] = 0; elb[j] = 0; }
                    else         { eha[j] = 0; ela[j] = 0; }
                }
                if (s_lo < 300) { MFMA3(acc0, eha, ela, bvh, bvl)
                                  MFMA3(acc1, ehb, elb, bvh, bvl) }
                else            { MFMA3(acc1, eha, ela, bvh, bvl)
                                  MFMA3(acc2, ehb, elb, bvh, bvl) }
            }
        }
    }

    #pragma unroll
    for (int sg = 0; sg < 3; ++sg)
        #pragma unroll
        for (int r = 0; r < 4; ++r) {
            float v = (sg == 0) ? ss0[r] : (sg == 1) ? ss1[r] : ss2[r];
            v += __shfl_down(v, 8, 16);
            v += __shfl_down(v, 4, 16);
            v += __shfl_down(v, 2, 16);
            v += __shfl_down(v, 1, 16);
            if (m == 0) SP[w][quad * 4 + r][sg] = v;
        }
    __syncthreads();

    #pragma unroll
    for (int r = 0; r < 4; ++r) {
        int t32 = tb * 16 + quad * 4 + r;
        int hd = hdb * 16 + m;
        PL[0 * 1152 + t32 * 36 + hd] = acc0[r];
        PL[1 * 1152 + t32 * 36 + hd] = acc1[r];
        PL[2 * 1152 + t32 * 36 + hd] = acc2[r];
    }
    __syncthreads();

    int tt = tid >> 3, q4 = tid & 7;
    float Pv[3][4];
    #pragma unroll
    for (int sg = 0; sg < 3; ++sg) {
        const float4 p = *(const float4*)&PL[sg * 1152 + tt * 36 + q4 * 4];
        Pv[sg][0] = p.x; Pv[sg][1] = p.y; Pv[sg][2] = p.z; Pv[sg][3] = p.w;
    }
    int tbe = tt >> 4, t16 = tt & 15;
    float S0 = SP[tbe][t16][0] + SP[tbe + 2][t16][0];
    float S1 = SP[tbe][t16][1] + SP[tbe + 2][t16][1];
    float S2 = SP[tbe][t16][2] + SP[tbe + 2][t16][2];

    int t_glob = t0 + tt;
    int g = (t_glob < 300) ? 0 : (t_glob < 550 ? 1 : 2);
    int b_ = bh >> 3, h_ = bh & 7;
    int row = t_glob * B + b_;
    int lslot = (row & 15) + ((q4 >> 1) << 4);
    int j0 = (q4 & 1) * 4;
    size_t fbase = (((size_t)(row >> 4) * 56 + h_) * 64 + lslot) * 8 + j0;
    const int masks[7] = {7, 3, 5, 6, 1, 2, 4};
    #pragma unroll
    for (int i = 0; i < 7; ++i) {
        int mm = masks[i];
        float n0 = 0.f, n1 = 0.f, n2 = 0.f, n3 = 0.f, den = 0.f;
        if (mm & 1) { n0 += Pv[0][0]; n1 += Pv[0][1]; n2 += Pv[0][2]; n3 += Pv[0][3]; den += S0; }
        if (mm & 2) { n0 += Pv[1][0]; n1 += Pv[1][1]; n2 += Pv[1][2]; n3 += Pv[1][3]; den += S1; }
        if (mm & 4) { n0 += Pv[2][0]; n1 += Pv[2][1]; n2 += Pv[2][2]; n3 += Pv[2][3]; den += S2; }
        float r = 1.f / den;
        int live = (mm >> g) & 1;
        float o[4];
        o[0] = live ? n0 * r : 0.f;
        o[1] = live ? n1 * r : 0.f;
        o[2] = live ? n2 * r : 0.f;
        o[3] = live ? n3 * r : 0.f;
        ushort4 hi4, lo4;
        unsigned short* hp = (unsigned short*)&hi4;
        unsigned short* lp = (unsigned short*)&lo4;
        #pragma unroll
        for (int j = 0; j < 4; ++j) {
            unsigned short hu = f2bf_u(o[j]);
            hp[j] = hu;
            lp[j] = f2bf_u(o[j] - bfu2f(hu));
        }
        size_t addr = fbase + (size_t)i * (8 * 64 * 8);
        *(ushort4*)&Ohi[addr] = hi4;
        *(ushort4*)&Olo[addr] = lo4;
    }
}

// DT hi/lo fragment-major (proven round-15: 32x32 tiles, grid (8,8,7)).
__global__ __launch_bounds__(256) void wcomb2_gemm_kernel(
    const float* __restrict__ Mtmp, const void* finalw,
    const int* __restrict__ flag,
    unsigned short* __restrict__ DThi, unsigned short* __restrict__ DTlo)
{
    int f32 = *flag;
    int bx = blockIdx.x;   // e tile 0..7
    int by = blockIdx.y;   // c tile 0..7
    int i  = blockIdx.z;   // branch 0..6
    int tid = threadIdx.x;
    int tx = tid & 15, ty = tid >> 4;
    int colbase = bx * 32, rowbase = by * 32;
    __shared__ __align__(16) float AsT[32][34];
    __shared__ __align__(16) float Bs[32][34];
    float acc[2][2] = {};

    for (int kb = 0; kb < 8; ++kb) {
        __syncthreads();
        #pragma unroll
        for (int l = 0; l < 4; ++l) {
            int idx = l * 256 + tid;
            int c = idx & 31, kk = idx >> 5;
            AsT[kk][c] = Mtmp[(size_t)i * 65536 + (kb * 32 + kk) * 256 + rowbase + c];
            int k2 = idx & 31, n = idx >> 5;
            Bs[k2][n] = ldu(finalw, (size_t)(colbase + n) * 256 + kb * 32 + k2, f32);
        }
        __syncthreads();
        #pragma unroll 8
        for (int kk = 0; kk < 32; ++kk) {
            const float2 av = *(const float2*)&AsT[kk][ty * 2];
            const float2 bv = *(const float2*)&Bs[kk][tx * 2];
            acc[0][0] += av.x * bv.x; acc[0][1] += av.x * bv.y;
            acc[1][0] += av.y * bv.x; acc[1][1] += av.y * bv.y;
        }
    }
    #pragma unroll
    for (int u = 0; u < 2; ++u)
        #pragma unroll
        for (int v = 0; v < 2; ++v) {
            int c = rowbase + ty * 2 + u, e = colbase + tx * 2 + v;
            float a = acc[u][v];
            unsigned short hu = f2bf_u(a);
            size_t fidx = (((size_t)(e >> 4) * 56 + i * 8 + (c >> 5)) * 64
                           + (e & 15) + (((c >> 3) & 3) << 4)) * 8 + (c & 7);
            DThi[fidx] = hu;
            DTlo[fidx] = f2bf_u(a - bfu2f(hu));
        }
}

// ---------------------------------------------------------------------------
// Bias path (proven round-5). c0 ALIASES Mtmp... NO — Mtmp now live until
// wcomb2; c0 uses the tail scratch beyond DT (within proven footprint).
// ---------------------------------------------------------------------------
__global__ __launch_bounds__(256) void bias1_kernel(
    const void* sl, const void* sa, const void* sv, const void* outb,
    const void* slb, const void* sab, const void* svb,
    const int* __restrict__ flag, float* __restrict__ c0)
{
    int f32 = *flag;
    int r2 = blockIdx.x, m = threadIdx.x;
    __shared__ float red[256];
    float acc = 0.f;
    #pragma unroll
    for (int i = 0; i < 7; ++i)
        acc += ldu(outb, i * 256 + m, f32) * gsum_load(i, r2, m, sl, sa, sv, f32);
    red[m] = acc;
    __syncthreads();
    for (int s = 128; s > 0; s >>= 1) {
        if (m < s) red[m] += red[m + s];
        __syncthreads();
    }
    if (m == 0)
        c0[r2] = red[0] + ldu(slb, r2, f32) + ldu(sab, r2, f32) + ldu(svb, r2, f32);
}

__global__ __launch_bounds__(256) void bias2_kernel(
    const float* __restrict__ c0, const void* finalw, const void* finalb,
    const int* __restrict__ flag, float* __restrict__ d0)
{
    int f32 = *flag;
    int e = blockIdx.x, r = threadIdx.x;
    __shared__ float red[256];
    red[r] = c0[r] * ldu(finalw, (size_t)e * 256 + r, f32);
    __syncthreads();
    for (int s = 128; s > 0; s >>= 1) {
        if (r < s) red[r] += red[r + s];
        __syncthreads();
    }
    if (r == 0)
        d0[e] = red[0] + ldu(finalb, e, f32);
}

// ---------------------------------------------------------------------------
// Kernel 4 (proven round-13, MFMA + fragment-major): result = O@Dstack + d0.
// ---------------------------------------------------------------------------
__global__ __launch_bounds__(256) void final_gemm_mfma_kernel(
    const unsigned short* __restrict__ Ohi, const unsigned short* __restrict__ Olo,
    const unsigned short* __restrict__ DThi, const unsigned short* __restrict__ DTlo,
    const float* __restrict__ d0, const int* __restrict__ flag,
    void* __restrict__ outv)
{
    int f32 = *flag;
    int bx = blockIdx.x;
    int by = blockIdx.y;
    int w  = threadIdx.x >> 6;
    int lane = threadIdx.x & 63;
    int m = lane & 15, quad = lane >> 4;
    int R0 = by * 16, C0 = bx * 64 + w * 16;

    int t0 = R0 >> 2, t1 = (R0 + 15) >> 2;
    int g0 = (t0 < 300) ? 0 : (t0 < 550 ? 1 : 2);
    int g1 = (t1 < 300) ? 0 : (t1 < 550 ? 1 : 2);
    int activeset = (1 << g0) | (1 << g1);
    const int masks[7] = {7, 3, 5, 6, 1, 2, 4};

    const unsigned short* Abase_h = Ohi + (size_t)by * 56 * 512 + lane * 8;
    const unsigned short* Abase_l = Olo + (size_t)by * 56 * 512 + lane * 8;
    const unsigned short* Bbase_h = DThi + (size_t)(bx * 4 + w) * 56 * 512 + lane * 8;
    const unsigned short* Bbase_l = DTlo + (size_t)(bx * 4 + w) * 56 * 512 + lane * 8;

    f32x4 acc = {};
    for (int i = 0; i < 7; ++i) {
        if (!(masks[i] & activeset)) continue;
        #pragma unroll
        for (int kb = 0; kb < 8; ++kb) {
            size_t off = (size_t)(i * 8 + kb) * 512;
            bf16x8 ah = *(const bf16x8*)(Abase_h + off);
            bf16x8 al = *(const bf16x8*)(Abase_l + off);
            bf16x8 bh = *(const bf16x8*)(Bbase_h + off);
            bf16x8 bl = *(const bf16x8*)(Bbase_l + off);
            acc = __builtin_amdgcn_mfma_f32_16x16x32_bf16(ah, bh, acc, 0, 0, 0);
            acc = __builtin_amdgcn_mfma_f32_16x16x32_bf16(ah, bl, acc, 0, 0, 0);
            acc = __builtin_amdgcn_mfma_f32_16x16x32_bf16(al, bh, acc, 0, 0, 0);
        }
    }
    float dv = d0[C0 + m];
    #pragma unroll
    for (int r = 0; r < 4; ++r) {
        int row = R0 + quad * 4 + r;
        int col = C0 + m;
        float val = acc[r] + dv;
        if (f32) ((float*)outv)[(size_t)row * 256 + col] = val;
        else ((__hip_bfloat16*)outv)[(size_t)row * 256 + col] = __float2bfloat16(val);
    }
}

// ---------------------------------------------------------------------------
extern "C" void kernel_launch(void* const* d_in, const int* in_sizes, int n_in,
                              void* d_out, int out_size, void* d_ws, size_t ws_size,
                              hipStream_t stream) {
    const void* query     = d_in[0];
    const void* key       = d_in[1];
    const void* value     = d_in[2];
    const void* in_proj_w = d_in[3];
    const void* in_proj_b = d_in[4];
    const void* out_w     = d_in[5];
    const void* out_b     = d_in[6];
    const void* s_l_w     = d_in[7];
    const void* s_l_b     = d_in[8];
    const void* s_a_w     = d_in[9];
    const void* s_a_b     = d_in[10];
    const void* s_v_w     = d_in[11];
    const void* s_v_b     = d_in[12];
    const void* final_w   = d_in[13];
    const void* final_b   = d_in[14];

    float* ws     = (float*)d_ws;
    float* qws    = ws;                 //   786432 f (q fp32)
    unsigned short* KGh = (unsigned short*)(ws + 786432);
    unsigned short* KGl = KGh + 786432;
    unsigned short* VGh = (unsigned short*)(ws + 1572864);
    unsigned short* VGl = VGh + 786432;
    // O region [2359296, 7864320): Ohi/Olo for attn+final; aliased by the
    // conversion buffers XF/WF/GF/OWF (all consumed before attn writes O).
    unsigned short* Ohi = (unsigned short*)(ws + 2359296);   // 5505024 bf16
    unsigned short* Olo = (unsigned short*)(ws + 5111808);   // 5505024 bf16
    unsigned short* XFh = (unsigned short*)(ws + 2359296);   // 2359296 bf16
    unsigned short* XFl = XFh + 2359296;                     // 2359296 bf16
    unsigned short* WFh = XFl + 2359296;                     //  196608 bf16
    unsigned short* WFl = WFh + 196608;                      //  196608 bf16
    unsigned short* GFh = (unsigned short*)(ws + 4915200);   //  458752 bf16
    unsigned short* GFl = GFh + 458752;
    unsigned short* OWFh = GFl + 458752;                     //  458752 bf16
    unsigned short* OWFl = OWFh + 458752;                    // ends f 5832704
    float* Mtmp   = ws + 7864320;       //   458752 f
    unsigned short* DThi = (unsigned short*)(ws + 8323072);  // 458752 bf16
    unsigned short* DTlo = (unsigned short*)(ws + 8552448);  // 458752 bf16
    float* d0     = ws + 8781824;       //      256 f
    int*   flag   = (int*)(ws + 8782080);  // 1 int — proven footprint HIGH-WATER
    float* c0     = Mtmp;               // ALIAS: Mtmp dead after wcomb2

    detect_kernel<<<1, 64, 0, stream>>>((const unsigned short*)query, flag);
    conv_kernel<<<1696, 256, 0, stream>>>(query, key, value, in_proj_w,
                                          s_l_w, s_a_w, s_v_w, out_w, flag,
                                          XFh, XFl, WFh, WFl,
                                          GFh, GFl, OWFh, OWFl);
    qkv_mfma_kernel<<<dim3(12, 192), 256, 0, stream>>>(XFh, XFl, WFh, WFl,
                                                       in_proj_b, flag, qws,
                                                       KGh, KGl, VGh, VGl);
    wcomb1_mfma_kernel<<<dim3(4, 16, 7), 256, 0, stream>>>(GFh, GFl, OWFh, OWFl,
                                                           Mtmp);
    attn_mfma_kernel<<<dim3(24, 32), 256, 0, stream>>>(qws, KGh, KGl, VGh, VGl,
                                                       Ohi, Olo);
    wcomb2_gemm_kernel<<<dim3(8, 8, 7), 256, 0, stream>>>(Mtmp, final_w, flag,
                                                          DThi, DTlo);
    bias1_kernel<<<256, 256, 0, stream>>>(s_l_w, s_a_w, s_v_w, out_b,
                                          s_l_b, s_a_b, s_v_b, flag, c0);
    bias2_kernel<<<256, 256, 0, stream>>>(c0, final_w, final_b, flag, d0);
    final_gemm_mfma_kernel<<<dim3(4, 192), 256, 0, stream>>>(Ohi, Olo, DThi, DTlo,
                                                             d0, flag, d_out);
}